// Round 6
// baseline (233.542 us; speedup 1.0000x reference)
//
#include <hip/hip_runtime.h>

#define HEADS 64
#define SEQ 2048
#define DIM 64
#define BR 128          // q rows per block (32 per wave, 4 waves)
#define BC 64           // keys per tile
#define NB (SEQ / BC)   // 32 tiles
#define NBH (NB / 2)    // 16 tiles per half (K-split)
#define TILE_U16 (BC * DIM)  // 4096 u16 = 8192 B per blob

// ws layout (u16 units for blobs, then floats):
//   [0, 32 MiB)        packed K/V^T blobs
//   [32, 96 MiB)       O partials: 2 x 8,388,608 floats
//   [96, 97 MiB)       l partials: 2 x 131,072 floats
#define BLOB_U16 16777216ull
#define OPART_F 8388608
#define LPART_F 131072
#define WS_NEED (32ull * 1024 * 1024 + 64ull * 1024 * 1024 + 1024ull * 1024)

typedef __attribute__((ext_vector_type(4))) float f32x4;
typedef __attribute__((ext_vector_type(8))) short s16x8;
typedef __attribute__((ext_vector_type(4))) unsigned int u32x4;

__device__ __forceinline__ unsigned pack2(float lo, float hi) {
  unsigned a = __builtin_bit_cast(unsigned, hi) + 0x8000u;
  unsigned b = __builtin_bit_cast(unsigned, lo) + 0x8000u;
  return __builtin_amdgcn_perm(a, b, 0x07060302u);
}

__device__ __forceinline__ unsigned cvt_pk_bf16(float lo, float hi) {
  unsigned r;
  asm("v_cvt_pk_bf16_f32 %0, %1, %2" : "=v"(r) : "v"(lo), "v"(hi));
  return r;
}

__device__ __forceinline__ void pl32_swap(unsigned &a, unsigned &b) {
  asm("v_permlane32_swap_b32 %0, %1" : "+v"(a), "+v"(b));
}
__device__ __forceinline__ void pl16_swap(unsigned &a, unsigned &b) {
  asm("v_permlane16_swap_b32 %0, %1" : "+v"(a), "+v"(b));
}

__device__ __forceinline__ s16x8 lds_read8(const unsigned short* p) {
  s16x8 r;
  __builtin_memcpy(&r, p, 16);
  return r;
}

__device__ __forceinline__ void async16(const unsigned short* g, unsigned short* l) {
  __builtin_amdgcn_global_load_lds(
      (const __attribute__((address_space(1))) unsigned int*)g,
      (__attribute__((address_space(3))) unsigned int*)l, 16, 0, 0);
}

// ---------------------------------------------------------------------------
// Pre-pass (unchanged, validated): one block per (head,kb).
//   K blob  (type 0): u16 idx key*64 + (d   ^ 8*(key&7))
//   V^T blob(type 1): u16 idx d*64   + (key ^ 8*(d&7))
// ---------------------------------------------------------------------------
__global__ __launch_bounds__(256) void prepack(const float* __restrict__ Kg,
                                               const float* __restrict__ Vg,
                                               unsigned short* __restrict__ ws) {
  __shared__ float vlds[BC * 65];
  const int hk = blockIdx.x;
  const int src = (hk >> 5) * (SEQ * DIM) + (hk & 31) * (BC * DIM);
  const float* kbase = Kg + src;
  const float* vbase = Vg + src;
  unsigned short* kout = ws + (hk * 2) * TILE_U16;
  unsigned short* vout = ws + (hk * 2 + 1) * TILE_U16;
  const int t = threadIdx.x;

#pragma unroll
  for (int j = 0; j < 4; ++j) {
    int o = t + 256 * j;
    int key = o >> 4;
    int d0 = 4 * (o & 15);
    float4 v = *(const float4*)(vbase + key * DIM + d0);
    __builtin_memcpy(&vlds[key * 65 + d0], &v, 16);
  }

#pragma unroll
  for (int j = 0; j < 4; ++j) {
    int o = t + 256 * j;
    int row = o >> 4;
    int d0 = (4 * (o & 15)) ^ (8 * (row & 7));
    float4 v = *(const float4*)(kbase + row * DIM + d0);
    uint2 val;
    val.x = pack2(v.x, v.y);
    val.y = pack2(v.z, v.w);
    __builtin_memcpy(kout + o * 4, &val, 8);
  }

  __syncthreads();

#pragma unroll
  for (int j = 0; j < 4; ++j) {
    int o = t + 256 * j;
    int d = o >> 4;
    int k0 = (4 * (o & 15)) ^ (8 * (d & 7));
    float a = vlds[(k0 + 0) * 65 + d];
    float b = vlds[(k0 + 1) * 65 + d];
    float e = vlds[(k0 + 2) * 65 + d];
    float f = vlds[(k0 + 3) * 65 + d];
    uint2 val;
    val.x = pack2(a, b);
    val.y = pack2(e, f);
    __builtin_memcpy(vout + o * 4, &val, 8);
  }
}

// ===========================================================================
// R11: K-split flash attention. R7/R8/R10 all measured 93 us with MfmaUtil
// ~30%, pure-VALU ~12%, ~58% issue slots empty at 2.7 waves/SIMD ->
// latency-bound, needs MORE WAVES. Grid is pinned at 4 blocks/CU by problem
// shape, so split the key range: each block does 16 tiles and emits
// unnormalized (O, l) partials (exactly linear thanks to the no-max exp2),
// grid 2048 -> LDS-capped ~5 blocks/CU (20 waves vs 10.7). A bandwidth-bound
// combine kernel sums partials and normalizes. Falls back to the validated
// single-pass kernel when ws is too small for partials.
// ===========================================================================
__global__ __launch_bounds__(256, 4) void fattn_split(
    const float* __restrict__ Qg, const unsigned short* __restrict__ ws,
    float* __restrict__ po, float* __restrict__ pl) {
  __shared__ __align__(16) unsigned short klds[2][TILE_U16];
  __shared__ __align__(16) unsigned short vtlds[2][TILE_U16];

  const int tid = threadIdx.x;
  const int w = tid >> 6;
  const int lane = tid & 63;
  const int q = lane >> 4;
  const int c = lane & 15;
  const int head = blockIdx.x & 63;        // head -> XCD affinity
  const int qblk = (blockIdx.x >> 6) & 15; // 0..15
  const int half = blockIdx.x >> 10;       // 0..1 key-range half
  const int hbase = head * (SEQ * DIM);
  const int qbase = qblk * BR + w * 32;

  const float qscale = 0.18033688011112042f;  // log2(e)/sqrt(64)

  // this half's 16 tiles start at blob index half*NBH
  const unsigned short* blobs =
      ws + head * (NB * 2 * TILE_U16) + (half * NBH) * (2 * TILE_U16);
  float* opart = po + half * OPART_F;
  float* lpart = pl + half * LPART_F;

  const int xoff0 = (q * 8) ^ ((c & 7) * 8);
  const int xoff1 = (32 + q * 8) ^ ((c & 7) * 8);

  auto stageK = [&](int t, unsigned short* dst) {
    const unsigned short* src = blobs + t * (2 * TILE_U16) + tid * 8;
    unsigned short* d = dst + w * 512;
    async16(src, d);
    async16(src + 2048, d + 2048);
  };
  auto stageV = [&](int t, unsigned short* dst) {
    const unsigned short* src = blobs + t * (2 * TILE_U16) + TILE_U16 + tid * 8;
    unsigned short* d = dst + w * 512;
    async16(src, d);
    async16(src + 2048, d + 2048);
  };

  stageK(0, klds[0]);

  s16x8 qf[2][2];
#pragma unroll
  for (int n = 0; n < 2; ++n) {
    const float* qp = Qg + hbase + (qbase + n * 16 + c) * DIM + q * 8;
#pragma unroll
    for (int kc = 0; kc < 2; ++kc) {
      float4 x = *(const float4*)(qp + kc * 32);
      float4 y = *(const float4*)(qp + kc * 32 + 4);
      u32x4 t = {pack2(x.x * qscale, x.y * qscale),
                 pack2(x.z * qscale, x.w * qscale),
                 pack2(y.x * qscale, y.y * qscale),
                 pack2(y.z * qscale, y.w * qscale)};
      qf[n][kc] = __builtin_bit_cast(s16x8, t);
    }
  }

  const f32x4 vzero = {0.f, 0.f, 0.f, 0.f};
  f32x4 lrun4[2] = {vzero, vzero};
  f32x4 oacc[4][2];
#pragma unroll
  for (int mt = 0; mt < 4; ++mt) {
    oacc[mt][0] = vzero;
    oacc[mt][1] = vzero;
  }

  s16x8 pfrA[2][2], pfrB[2][2];

  auto qk_softmax = [&](const unsigned short* kbuf, s16x8 (&pfr)[2][2]) {
    f32x4 st[4][2];
#pragma unroll
    for (int kt = 0; kt < 4; ++kt) {
      st[kt][0] = vzero;
      st[kt][1] = vzero;
    }
#pragma unroll
    for (int kc = 0; kc < 2; ++kc) {
      const int off = kc ? xoff1 : xoff0;
#pragma unroll
      for (int kt = 0; kt < 4; ++kt) {
        s16x8 kf = lds_read8(&kbuf[(c + 16 * kt) * 64 + off]);
        st[kt][0] = __builtin_amdgcn_mfma_f32_16x16x32_bf16(kf, qf[0][kc], st[kt][0], 0, 0, 0);
        st[kt][1] = __builtin_amdgcn_mfma_f32_16x16x32_bf16(kf, qf[1][kc], st[kt][1], 0, 0, 0);
      }
    }
#pragma unroll
    for (int n = 0; n < 2; ++n) {
#pragma unroll
      for (int kt = 0; kt < 4; ++kt)
#pragma unroll
        for (int r = 0; r < 4; ++r)
          st[kt][n][r] = __builtin_amdgcn_exp2f(st[kt][n][r]);
      lrun4[n] += (st[0][n] + st[1][n]) + (st[2][n] + st[3][n]);

      unsigned w00 = cvt_pk_bf16(st[0][n][0], st[0][n][1]);
      unsigned w10 = cvt_pk_bf16(st[1][n][0], st[1][n][1]);
      unsigned w20 = cvt_pk_bf16(st[2][n][0], st[2][n][1]);
      unsigned w30 = cvt_pk_bf16(st[3][n][0], st[3][n][1]);
      unsigned w01 = cvt_pk_bf16(st[0][n][2], st[0][n][3]);
      unsigned w11 = cvt_pk_bf16(st[1][n][2], st[1][n][3]);
      unsigned w21 = cvt_pk_bf16(st[2][n][2], st[2][n][3]);
      unsigned w31 = cvt_pk_bf16(st[3][n][2], st[3][n][3]);
      pl32_swap(w00, w10);
      pl32_swap(w20, w30);
      pl32_swap(w01, w11);
      pl32_swap(w21, w31);
      pl16_swap(w00, w10);
      pl16_swap(w20, w30);
      pl16_swap(w01, w11);
      pl16_swap(w21, w31);
      u32x4 f0 = {w00, w01, w10, w11};
      u32x4 f1 = {w20, w21, w30, w31};
      pfr[n][0] = __builtin_bit_cast(s16x8, f0);
      pfr[n][1] = __builtin_bit_cast(s16x8, f1);
    }
  };

  auto do_pv = [&](const unsigned short* vbuf, const s16x8 (&pfr)[2][2]) {
#pragma unroll
    for (int kc = 0; kc < 2; ++kc) {
      const int off = kc ? xoff1 : xoff0;
#pragma unroll
      for (int mt = 0; mt < 4; ++mt) {
        s16x8 vf = lds_read8(&vbuf[(c + 16 * mt) * 64 + off]);
        oacc[mt][0] = __builtin_amdgcn_mfma_f32_16x16x32_bf16(vf, pfr[0][kc], oacc[mt][0], 0, 0, 0);
        oacc[mt][1] = __builtin_amdgcn_mfma_f32_16x16x32_bf16(vf, pfr[1][kc], oacc[mt][1], 0, 0, 0);
      }
    }
  };

  __syncthreads();  // drains tile-0 K DMA

  // iter 0 (peeled)
  stageK(1, klds[1]);
  stageV(0, vtlds[0]);
  qk_softmax(klds[0], pfrA);
  __syncthreads();

  // steady state: pairs kb = 1,3,...,NBH-3
  for (int kb = 1; kb < NBH - 1; kb += 2) {
    stageK(kb + 1, klds[0]);
    stageV(kb, vtlds[1]);
    qk_softmax(klds[1], pfrB);
    do_pv(vtlds[0], pfrA);
    __syncthreads();
    stageK(kb + 2, klds[1]);
    stageV(kb + 1, vtlds[0]);
    qk_softmax(klds[0], pfrA);
    do_pv(vtlds[1], pfrB);
    __syncthreads();
  }

  // final iter kb = NBH-1
  stageV(NBH - 1, vtlds[1]);
  qk_softmax(klds[1], pfrB);
  do_pv(vtlds[0], pfrA);
  __syncthreads();
  do_pv(vtlds[1], pfrB);

  // epilogue: write raw O partial + reduced l partial (no normalization)
#pragma unroll
  for (int n = 0; n < 2; ++n) {
    f32x4 l4 = lrun4[n];
    float l = (l4.x + l4.y) + (l4.z + l4.w);
    l += __shfl_xor(l, 16);
    l += __shfl_xor(l, 32);
    int row = qbase + 16 * n + c;
    if (lane < 16) lpart[head * SEQ + row] = l;
#pragma unroll
    for (int mt = 0; mt < 4; ++mt)
      *(f32x4*)(opart + hbase + row * DIM + 16 * mt + 4 * q) = oacc[mt][n];
  }
}

// combine: O = (O0 + O1) / (l0 + l1); 2048 blocks x 256 thr x 4 f32x4
__global__ __launch_bounds__(256) void combine(const float* __restrict__ po,
                                               const float* __restrict__ pl,
                                               float* __restrict__ Og) {
  const int t = blockIdx.x * 256 + threadIdx.x;
#pragma unroll
  for (int i = 0; i < 4; ++i) {
    const int v = t + i * 524288;        // f32x4 index, 4*524288 = 2,097,152 total
    const int lidx = v >> 4;             // head*SEQ + row
    f32x4 a = *(const f32x4*)(po + 4 * v);
    f32x4 b = *(const f32x4*)(po + OPART_F + 4 * v);
    float inv = 1.0f / (pl[lidx] + pl[LPART_F + lidx]);
    f32x4 r = (a + b) * inv;
    *(f32x4*)(Og + 4 * v) = r;
  }
}

// ---------------------------------------------------------------------------
// Fallback single-pass kernel (R10, validated) for small workspaces.
// ---------------------------------------------------------------------------
__global__ __launch_bounds__(256, 4) void fattn_full(
    const float* __restrict__ Qg, const unsigned short* __restrict__ ws,
    float* __restrict__ Og) {
  __shared__ __align__(16) unsigned short klds[2][TILE_U16];
  __shared__ __align__(16) unsigned short vtlds[2][TILE_U16];

  const int tid = threadIdx.x;
  const int w = tid >> 6;
  const int lane = tid & 63;
  const int q = lane >> 4;
  const int c = lane & 15;
  const int head = blockIdx.x & 63;
  const int qblk = blockIdx.x >> 6;
  const int hbase = head * (SEQ * DIM);
  const int qbase = qblk * BR + w * 32;

  const float qscale = 0.18033688011112042f;

  const unsigned short* blobs = ws + head * (NB * 2 * TILE_U16);

  const int xoff0 = (q * 8) ^ ((c & 7) * 8);
  const int xoff1 = (32 + q * 8) ^ ((c & 7) * 8);

  auto stageK = [&](int t, unsigned short* dst) {
    const unsigned short* src = blobs + t * (2 * TILE_U16) + tid * 8;
    unsigned short* d = dst + w * 512;
    async16(src, d);
    async16(src + 2048, d + 2048);
  };
  auto stageV = [&](int t, unsigned short* dst) {
    const unsigned short* src = blobs + t * (2 * TILE_U16) + TILE_U16 + tid * 8;
    unsigned short* d = dst + w * 512;
    async16(src, d);
    async16(src + 2048, d + 2048);
  };

  stageK(0, klds[0]);

  s16x8 qf[2][2];
#pragma unroll
  for (int n = 0; n < 2; ++n) {
    const float* qp = Qg + hbase + (qbase + n * 16 + c) * DIM + q * 8;
#pragma unroll
    for (int kc = 0; kc < 2; ++kc) {
      float4 x = *(const float4*)(qp + kc * 32);
      float4 y = *(const float4*)(qp + kc * 32 + 4);
      u32x4 t = {pack2(x.x * qscale, x.y * qscale),
                 pack2(x.z * qscale, x.w * qscale),
                 pack2(y.x * qscale, y.y * qscale),
                 pack2(y.z * qscale, y.w * qscale)};
      qf[n][kc] = __builtin_bit_cast(s16x8, t);
    }
  }

  const f32x4 vzero = {0.f, 0.f, 0.f, 0.f};
  f32x4 lrun4[2] = {vzero, vzero};
  f32x4 oacc[4][2];
#pragma unroll
  for (int mt = 0; mt < 4; ++mt) {
    oacc[mt][0] = vzero;
    oacc[mt][1] = vzero;
  }

  s16x8 pfrA[2][2], pfrB[2][2];

  auto qk_softmax = [&](const unsigned short* kbuf, s16x8 (&pfr)[2][2]) {
    f32x4 st[4][2];
#pragma unroll
    for (int kt = 0; kt < 4; ++kt) {
      st[kt][0] = vzero;
      st[kt][1] = vzero;
    }
#pragma unroll
    for (int kc = 0; kc < 2; ++kc) {
      const int off = kc ? xoff1 : xoff0;
#pragma unroll
      for (int kt = 0; kt < 4; ++kt) {
        s16x8 kf = lds_read8(&kbuf[(c + 16 * kt) * 64 + off]);
        st[kt][0] = __builtin_amdgcn_mfma_f32_16x16x32_bf16(kf, qf[0][kc], st[kt][0], 0, 0, 0);
        st[kt][1] = __builtin_amdgcn_mfma_f32_16x16x32_bf16(kf, qf[1][kc], st[kt][1], 0, 0, 0);
      }
    }
#pragma unroll
    for (int n = 0; n < 2; ++n) {
#pragma unroll
      for (int kt = 0; kt < 4; ++kt)
#pragma unroll
        for (int r = 0; r < 4; ++r)
          st[kt][n][r] = __builtin_amdgcn_exp2f(st[kt][n][r]);
      lrun4[n] += (st[0][n] + st[1][n]) + (st[2][n] + st[3][n]);

      unsigned w00 = cvt_pk_bf16(st[0][n][0], st[0][n][1]);
      unsigned w10 = cvt_pk_bf16(st[1][n][0], st[1][n][1]);
      unsigned w20 = cvt_pk_bf16(st[2][n][0], st[2][n][1]);
      unsigned w30 = cvt_pk_bf16(st[3][n][0], st[3][n][1]);
      unsigned w01 = cvt_pk_bf16(st[0][n][2], st[0][n][3]);
      unsigned w11 = cvt_pk_bf16(st[1][n][2], st[1][n][3]);
      unsigned w21 = cvt_pk_bf16(st[2][n][2], st[2][n][3]);
      unsigned w31 = cvt_pk_bf16(st[3][n][2], st[3][n][3]);
      pl32_swap(w00, w10);
      pl32_swap(w20, w30);
      pl32_swap(w01, w11);
      pl32_swap(w21, w31);
      pl16_swap(w00, w10);
      pl16_swap(w20, w30);
      pl16_swap(w01, w11);
      pl16_swap(w21, w31);
      u32x4 f0 = {w00, w01, w10, w11};
      u32x4 f1 = {w20, w21, w30, w31};
      pfr[n][0] = __builtin_bit_cast(s16x8, f0);
      pfr[n][1] = __builtin_bit_cast(s16x8, f1);
    }
  };

  auto do_pv = [&](const unsigned short* vbuf, const s16x8 (&pfr)[2][2]) {
#pragma unroll
    for (int kc = 0; kc < 2; ++kc) {
      const int off = kc ? xoff1 : xoff0;
#pragma unroll
      for (int mt = 0; mt < 4; ++mt) {
        s16x8 vf = lds_read8(&vbuf[(c + 16 * mt) * 64 + off]);
        oacc[mt][0] = __builtin_amdgcn_mfma_f32_16x16x32_bf16(vf, pfr[0][kc], oacc[mt][0], 0, 0, 0);
        oacc[mt][1] = __builtin_amdgcn_mfma_f32_16x16x32_bf16(vf, pfr[1][kc], oacc[mt][1], 0, 0, 0);
      }
    }
  };

  __syncthreads();

  stageK(1, klds[1]);
  stageV(0, vtlds[0]);
  qk_softmax(klds[0], pfrA);
  __syncthreads();

  for (int kb = 1; kb < NB - 1; kb += 2) {
    stageK(kb + 1, klds[0]);
    stageV(kb, vtlds[1]);
    qk_softmax(klds[1], pfrB);
    do_pv(vtlds[0], pfrA);
    __syncthreads();
    stageK(kb + 2, klds[1]);
    stageV(kb + 1, vtlds[0]);
    qk_softmax(klds[0], pfrA);
    do_pv(vtlds[1], pfrB);
    __syncthreads();
  }

  stageV(NB - 1, vtlds[1]);
  qk_softmax(klds[1], pfrB);
  do_pv(vtlds[0], pfrA);
  __syncthreads();
  do_pv(vtlds[1], pfrB);

#pragma unroll
  for (int n = 0; n < 2; ++n) {
    f32x4 l4 = lrun4[n];
    float l = (l4.x + l4.y) + (l4.z + l4.w);
    l += __shfl_xor(l, 16);
    l += __shfl_xor(l, 32);
    float inv = 1.0f / l;
    int row = qbase + 16 * n + c;
#pragma unroll
    for (int mt = 0; mt < 4; ++mt) {
      f32x4 r = oacc[mt][n] * inv;
      *(f32x4*)(Og + hbase + row * DIM + 16 * mt + 4 * q) = r;
    }
  }
}

extern "C" void kernel_launch(void* const* d_in, const int* in_sizes, int n_in,
                              void* d_out, int out_size, void* d_ws, size_t ws_size,
                              hipStream_t stream) {
  const float* Q = (const float*)d_in[0];
  const float* K = (const float*)d_in[1];
  const float* V = (const float*)d_in[2];
  float* O = (float*)d_out;
  unsigned short* ws = (unsigned short*)d_ws;
  hipLaunchKernelGGL(prepack, dim3(HEADS * NB), dim3(256), 0, stream, K, V, ws);
  if (ws_size >= WS_NEED) {
    float* po = (float*)(ws + BLOB_U16);
    float* pl = po + 2 * OPART_F;
    hipLaunchKernelGGL(fattn_split, dim3(2 * HEADS * (SEQ / BR)), dim3(256), 0, stream,
                       Q, (const unsigned short*)ws, po, pl);
    hipLaunchKernelGGL(combine, dim3(2048), dim3(256), 0, stream,
                       (const float*)po, (const float*)pl, O);
  } else {
    hipLaunchKernelGGL(fattn_full, dim3(HEADS * (SEQ / BR)), dim3(256), 0, stream,
                       Q, (const unsigned short*)ws, O);
  }
}

// Round 7
// 197.921 us; speedup vs baseline: 1.1800x; 1.1800x over previous
//
#include <hip/hip_runtime.h>

#define HEADS 64
#define SEQ 2048
#define DIM 64
#define BR 256          // q rows per block (32 per wave, 8 waves)
#define BC 64           // keys per tile
#define NB (SEQ / BC)   // 32 tiles
#define TILE_U16 (BC * DIM)  // 4096 u16 = 8192 B per blob

typedef __attribute__((ext_vector_type(4))) float f32x4;
typedef __attribute__((ext_vector_type(8))) short s16x8;
typedef __attribute__((ext_vector_type(4))) unsigned int u32x4;

// pack two fp32 -> two bf16 (round-half-up) in one v_perm
__device__ __forceinline__ unsigned pack2(float lo, float hi) {
  unsigned a = __builtin_bit_cast(unsigned, hi) + 0x8000u;
  unsigned b = __builtin_bit_cast(unsigned, lo) + 0x8000u;
  return __builtin_amdgcn_perm(a, b, 0x07060302u);
}

// single-instruction packed fp32->bf16 (RNE)
__device__ __forceinline__ unsigned cvt_pk_bf16(float lo, float hi) {
  unsigned r;
  asm("v_cvt_pk_bf16_f32 %0, %1, %2" : "=v"(r) : "v"(lo), "v"(hi));
  return r;
}

// gfx950 cross-lane half-register swaps (both operands read AND written)
__device__ __forceinline__ void pl32_swap(unsigned &a, unsigned &b) {
  asm("v_permlane32_swap_b32 %0, %1" : "+v"(a), "+v"(b));
}
__device__ __forceinline__ void pl16_swap(unsigned &a, unsigned &b) {
  asm("v_permlane16_swap_b32 %0, %1" : "+v"(a), "+v"(b));
}

__device__ __forceinline__ s16x8 lds_read8(const unsigned short* p) {
  s16x8 r;
  __builtin_memcpy(&r, p, 16);
  return r;
}

// async global->LDS DMA, 16 B per lane (wave-uniform LDS base + lane*16)
__device__ __forceinline__ void async16(const unsigned short* g, unsigned short* l) {
  __builtin_amdgcn_global_load_lds(
      (const __attribute__((address_space(1))) unsigned int*)g,
      (__attribute__((address_space(3))) unsigned int*)l, 16, 0, 0);
}

// ---------------------------------------------------------------------------
// Pre-pass (unchanged, validated): one block per (head,kb).
//   K blob  (type 0): u16 idx key*64 + (d   ^ 8*(key&7))
//   V^T blob(type 1): u16 idx d*64   + (key ^ 8*(d&7))
// ---------------------------------------------------------------------------
__global__ __launch_bounds__(256) void prepack(const float* __restrict__ Kg,
                                               const float* __restrict__ Vg,
                                               unsigned short* __restrict__ ws) {
  __shared__ float vlds[BC * 65];
  const int hk = blockIdx.x;
  const int src = (hk >> 5) * (SEQ * DIM) + (hk & 31) * (BC * DIM);
  const float* kbase = Kg + src;
  const float* vbase = Vg + src;
  unsigned short* kout = ws + (hk * 2) * TILE_U16;
  unsigned short* vout = ws + (hk * 2 + 1) * TILE_U16;
  const int t = threadIdx.x;

#pragma unroll
  for (int j = 0; j < 4; ++j) {
    int o = t + 256 * j;
    int key = o >> 4;
    int d0 = 4 * (o & 15);
    float4 v = *(const float4*)(vbase + key * DIM + d0);
    __builtin_memcpy(&vlds[key * 65 + d0], &v, 16);
  }

#pragma unroll
  for (int j = 0; j < 4; ++j) {
    int o = t + 256 * j;
    int row = o >> 4;
    int d0 = (4 * (o & 15)) ^ (8 * (row & 7));
    float4 v = *(const float4*)(kbase + row * DIM + d0);
    uint2 val;
    val.x = pack2(v.x, v.y);
    val.y = pack2(v.z, v.w);
    __builtin_memcpy(kout + o * 4, &val, 8);
  }

  __syncthreads();

#pragma unroll
  for (int j = 0; j < 4; ++j) {
    int o = t + 256 * j;
    int d = o >> 4;
    int k0 = (4 * (o & 15)) ^ (8 * (d & 7));
    float a = vlds[(k0 + 0) * 65 + d];
    float b = vlds[(k0 + 1) * 65 + d];
    float e = vlds[(k0 + 2) * 65 + d];
    float f = vlds[(k0 + 3) * 65 + d];
    uint2 val;
    val.x = pack2(a, b);
    val.y = pack2(e, f);
    __builtin_memcpy(vout + o * 4, &val, 8);
  }
}

// ---------------------------------------------------------------------------
// R12: counted-vmcnt pipeline (T3/T4). All prior variants (R1/R7/R10/R11)
// sit at 93-96 us with MfmaUtil ~30% regardless of schedule/occupancy: the
// common element is __syncthreads()'s implied s_waitcnt vmcnt(0), which
// drains the tile DMA issued at the START of the same iteration (m233's
// "2-phase stall"). Fix: triple-buffer K/V (48 KB), prefetch distance 2,
// and end each iteration with s_waitcnt vmcnt(2) + raw s_barrier — tile
// kb+1 (issued a full iteration ago) is ready, tile kb+2's 2 DMAs stay in
// flight ACROSS the barrier. In-loop vmcnt traffic is exactly the 2
// DMAs/iter, so counts are exact. Tail peeled: vmcnt(0) at kb=30, no
// barrier after kb=31.
// ---------------------------------------------------------------------------
__global__ __launch_bounds__(512, 4) void fattn_kernel(
    const float* __restrict__ Qg, const unsigned short* __restrict__ ws,
    float* __restrict__ Og) {
  __shared__ __align__(16) unsigned short klds[3][TILE_U16];   // 3 x 8 KB
  __shared__ __align__(16) unsigned short vtlds[3][TILE_U16];  // 3 x 8 KB

  const int tid = threadIdx.x;
  const int w = tid >> 6;
  const int lane = tid & 63;
  const int q = lane >> 4;  // quad
  const int c = lane & 15;  // m/n index within 16
  const int head = blockIdx.x & 63;  // head h -> XCD h%8 (L2 affinity)
  const int qblk = blockIdx.x >> 6;  // 0..7
  const int hbase = head * (SEQ * DIM);
  const int qbase = qblk * BR + w * 32;

  const float qscale = 0.18033688011112042f;  // log2(e)/sqrt(64), folded into Q

  const unsigned short* blobs = ws + head * (NB * 2 * TILE_U16);

  const int xoff0 = (q * 8) ^ ((c & 7) * 8);
  const int xoff1 = (32 + q * 8) ^ ((c & 7) * 8);

  // 512 threads stage one 8 KB blob in a single async16 sweep
  auto stageK = [&](int t, int buf) {
    async16(blobs + t * (2 * TILE_U16) + tid * 8, &klds[buf][w * 512]);
  };
  auto stageV = [&](int t, int buf) {
    async16(blobs + t * (2 * TILE_U16) + TILE_U16 + tid * 8, &vtlds[buf][w * 512]);
  };

  // prologue: tiles 0 and 1 in flight
  stageK(0, 0);
  stageV(0, 0);
  stageK(1, 1);
  stageV(1, 1);

  // Q fragments (B operand of S^T = K.Q^T): lane holds Q[row=c+16n][d=q*8+j+32kc]
  s16x8 qf[2][2];
#pragma unroll
  for (int n = 0; n < 2; ++n) {
    const float* qp = Qg + hbase + (qbase + n * 16 + c) * DIM + q * 8;
#pragma unroll
    for (int kc = 0; kc < 2; ++kc) {
      float4 x = *(const float4*)(qp + kc * 32);
      float4 y = *(const float4*)(qp + kc * 32 + 4);
      u32x4 t = {pack2(x.x * qscale, x.y * qscale),
                 pack2(x.z * qscale, x.w * qscale),
                 pack2(y.x * qscale, y.y * qscale),
                 pack2(y.z * qscale, y.w * qscale)};
      qf[n][kc] = __builtin_bit_cast(s16x8, t);
    }
  }

  const f32x4 vzero = {0.f, 0.f, 0.f, 0.f};
  f32x4 lrun4[2] = {vzero, vzero};
  f32x4 oacc[4][2];
#pragma unroll
  for (int mt = 0; mt < 4; ++mt) {
    oacc[mt][0] = vzero;
    oacc[mt][1] = vzero;
  }

  s16x8 pfr[2][2];

  // QK^T + exp2 + l accumulate + in-register quad transpose -> PV fragments
  auto qk_softmax = [&](const unsigned short* kbuf) {
    f32x4 st[4][2];
#pragma unroll
    for (int kt = 0; kt < 4; ++kt) {
      st[kt][0] = vzero;
      st[kt][1] = vzero;
    }
#pragma unroll
    for (int kc = 0; kc < 2; ++kc) {
      const int off = kc ? xoff1 : xoff0;
#pragma unroll
      for (int kt = 0; kt < 4; ++kt) {
        s16x8 kf = lds_read8(&kbuf[(c + 16 * kt) * 64 + off]);
        st[kt][0] = __builtin_amdgcn_mfma_f32_16x16x32_bf16(kf, qf[0][kc], st[kt][0], 0, 0, 0);
        st[kt][1] = __builtin_amdgcn_mfma_f32_16x16x32_bf16(kf, qf[1][kc], st[kt][1], 0, 0, 0);
      }
    }
#pragma unroll
    for (int n = 0; n < 2; ++n) {
#pragma unroll
      for (int kt = 0; kt < 4; ++kt)
#pragma unroll
        for (int r = 0; r < 4; ++r)
          st[kt][n][r] = __builtin_amdgcn_exp2f(st[kt][n][r]);
      lrun4[n] += (st[0][n] + st[1][n]) + (st[2][n] + st[3][n]);

      unsigned w00 = cvt_pk_bf16(st[0][n][0], st[0][n][1]);
      unsigned w10 = cvt_pk_bf16(st[1][n][0], st[1][n][1]);
      unsigned w20 = cvt_pk_bf16(st[2][n][0], st[2][n][1]);
      unsigned w30 = cvt_pk_bf16(st[3][n][0], st[3][n][1]);
      unsigned w01 = cvt_pk_bf16(st[0][n][2], st[0][n][3]);
      unsigned w11 = cvt_pk_bf16(st[1][n][2], st[1][n][3]);
      unsigned w21 = cvt_pk_bf16(st[2][n][2], st[2][n][3]);
      unsigned w31 = cvt_pk_bf16(st[3][n][2], st[3][n][3]);
      pl32_swap(w00, w10);
      pl32_swap(w20, w30);
      pl32_swap(w01, w11);
      pl32_swap(w21, w31);
      pl16_swap(w00, w10);
      pl16_swap(w20, w30);
      pl16_swap(w01, w11);
      pl16_swap(w21, w31);
      u32x4 f0 = {w00, w01, w10, w11};
      u32x4 f1 = {w20, w21, w30, w31};
      pfr[n][0] = __builtin_bit_cast(s16x8, f0);
      pfr[n][1] = __builtin_bit_cast(s16x8, f1);
    }
  };

  // O^T += V^T . P^T
  auto do_pv = [&](const unsigned short* vbuf) {
#pragma unroll
    for (int kc = 0; kc < 2; ++kc) {
      const int off = kc ? xoff1 : xoff0;
#pragma unroll
      for (int mt = 0; mt < 4; ++mt) {
        s16x8 vf = lds_read8(&vbuf[(c + 16 * mt) * 64 + off]);
        oacc[mt][0] = __builtin_amdgcn_mfma_f32_16x16x32_bf16(vf, pfr[0][kc], oacc[mt][0], 0, 0, 0);
        oacc[mt][1] = __builtin_amdgcn_mfma_f32_16x16x32_bf16(vf, pfr[1][kc], oacc[mt][1], 0, 0, 0);
      }
    }
  };

  // prologue sync: everything except (at most) tile 1's 2 DMAs drained ->
  // tile 0 ready. (In-order vmcnt: Q loads issued after the DMAs, so this
  // is conservative; prologue-only cost.)
  asm volatile("s_waitcnt vmcnt(2)" ::: "memory");
  __builtin_amdgcn_s_barrier();
  __builtin_amdgcn_sched_barrier(0);

  // one iteration at buffer p (kb % 3 == p); issues tile kb+2 if it exists.
  auto body = [&](int kb, int p) {
    if (kb + 2 < NB) {
      stageK(kb + 2, (p + 2) % 3);
      stageV(kb + 2, (p + 2) % 3);
    }
    __builtin_amdgcn_sched_barrier(0);  // pin DMA issue before compute
    qk_softmax(klds[p]);
    do_pv(vtlds[p]);
    // counted wait: tile kb+1 ready, tile kb+2's 2 DMAs stay in flight
    if (kb + 2 < NB)
      asm volatile("s_waitcnt vmcnt(2)" ::: "memory");
    else
      asm volatile("s_waitcnt vmcnt(0)" ::: "memory");
    __builtin_amdgcn_s_barrier();
    __builtin_amdgcn_sched_barrier(0);
  };

  // kb = 0..29 in triples; kb=30 (no issue, vmcnt(0)); kb=31 (no barrier)
  for (int kb = 0; kb < NB - 2; kb += 3) {
    body(kb + 0, 0);
    body(kb + 1, 1);
    body(kb + 2, 2);
  }
  body(NB - 2, 0);          // kb=30: issues nothing, drains tile 31
  qk_softmax(klds[1]);      // kb=31 (31 % 3 == 1), no trailing barrier
  do_pv(vtlds[1]);

  // ---- epilogue: reduce l (4 lanes of lrun4, then across quads), O = O^T / l
#pragma unroll
  for (int n = 0; n < 2; ++n) {
    f32x4 l4 = lrun4[n];
    float l = (l4.x + l4.y) + (l4.z + l4.w);
    l += __shfl_xor(l, 16);
    l += __shfl_xor(l, 32);
    float inv = 1.0f / l;
    int row = qbase + 16 * n + c;
#pragma unroll
    for (int mt = 0; mt < 4; ++mt) {
      f32x4 r = oacc[mt][n] * inv;
      *(f32x4*)(Og + hbase + row * DIM + 16 * mt + 4 * q) = r;
    }
  }
}

extern "C" void kernel_launch(void* const* d_in, const int* in_sizes, int n_in,
                              void* d_out, int out_size, void* d_ws, size_t ws_size,
                              hipStream_t stream) {
  const float* Q = (const float*)d_in[0];
  const float* K = (const float*)d_in[1];
  const float* V = (const float*)d_in[2];
  float* O = (float*)d_out;
  unsigned short* ws = (unsigned short*)d_ws;  // needs 32 MiB
  hipLaunchKernelGGL(prepack, dim3(HEADS * NB), dim3(256), 0, stream, K, V, ws);
  hipLaunchKernelGGL(fattn_kernel, dim3(HEADS * (SEQ / BR)), dim3(512), 0, stream,
                     Q, (const unsigned short*)ws, O);
}